// Round 8
// baseline (197.151 us; speedup 1.0000x reference)
//
#include <hip/hip_runtime.h>

// ---------------------------------------------------------------------------
// MultiHeadAttention: B=2, S=2048, H=16, Dh=64, D=1024, causal mask, fp32 I/O.
// R18: attention staging is PURE DMA for both K and V, double-buffered,
//      one barrier per pair.  V LDS layout changed from permuted-4-short to
//      LINEAR 16B chunks with row-XOR swizzle (c^(d&7)) so global_load_lds
//      can stage it (pre-swizzled per-lane source, linear dest — rule 21);
//      PV A-frags become two ds_read_b64 (uniform 4-touch/bank = optimal).
//      Removes R17's V register round-trip (loadV/writeV/vpre): no prefetch
//      VGPRs, no ds_writes, no staging VALU.  8 waves x 16 q-rows, 64KB LDS,
//      2 blocks/CU.  Softmax/masking/epilogue byte-identical to R16/R17.
//      GEMMs unchanged (R14 conflict-free swizzled staging, verified).
// ---------------------------------------------------------------------------

#define B_   2
#define S_   2048
#define H_   16
#define DH_  64
#define D_   1024
#define M_   (B_ * S_)          // 4096 rows

typedef __attribute__((ext_vector_type(8))) short short8;
typedef __attribute__((ext_vector_type(4))) short short4_t;
typedef float v4f __attribute__((ext_vector_type(4)));

__device__ __forceinline__ short f2bf(float f) {
    union { float f; unsigned u; } v; v.f = f;
    unsigned r = v.u + 0x7fffu + ((v.u >> 16) & 1u);  // round-to-nearest-even
    return (short)(r >> 16);
}

#if __has_builtin(__builtin_amdgcn_exp2f)
#define EXP2(x) __builtin_amdgcn_exp2f(x)
#else
#define EXP2(x) exp2f(x)
#endif

// pack two f32 -> dword of two truncated bf16 (low short = a, high = b)
__device__ __forceinline__ unsigned pack2(float a, float b) {
    return (__float_as_uint(a) >> 16) | (__float_as_uint(b) & 0xFFFF0000u);
}

// async 16B/lane global -> LDS DMA (lane l deposits at lds + l*16)
__device__ __forceinline__ void gl2lds16(const short* g, short* l) {
    __builtin_amdgcn_global_load_lds(
        (const __attribute__((address_space(1))) unsigned int*)g,
        (__attribute__((address_space(3))) unsigned int*)l,
        16, 0, 0);
}

// ---------------------------------------------------------------------------
// Kernel 1: cast X and Wq,Wk,Wv,Wo fp32 -> bf16.  8 elems/thread, 16B stores.
// ---------------------------------------------------------------------------
__global__ __launch_bounds__(256) void cast_kernel(
    const float* __restrict__ X,
    const float* __restrict__ Wq, const float* __restrict__ Wk,
    const float* __restrict__ Wv, const float* __restrict__ Wo,
    short* __restrict__ Xb, short* __restrict__ Wb)
{
    const int NX8 = (M_ * D_) / 8;      // 524,288
    const int NW8 = (D_ * D_) / 8;      // 131,072
    int idx = blockIdx.x * 256 + threadIdx.x;   // 1,048,576 threads

    const float* src; short* dst; int off;
    if (idx < NX8) { src = X; dst = Xb; off = idx; }
    else {
        int r = idx - NX8;
        int sel = r >> 17;
        int o = r & (NW8 - 1);
        src = (sel == 0) ? Wq : (sel == 1) ? Wk : (sel == 2) ? Wv : Wo;
        dst = Wb + sel * (D_ * D_);
        off = o;
    }
    float4 f0 = ((const float4*)src)[off * 2];
    float4 f1 = ((const float4*)src)[off * 2 + 1];
    short8 s;
    s[0] = f2bf(f0.x); s[1] = f2bf(f0.y); s[2] = f2bf(f0.z); s[3] = f2bf(f0.w);
    s[4] = f2bf(f1.x); s[5] = f2bf(f1.y); s[6] = f2bf(f1.z); s[7] = f2bf(f1.w);
    *(short8*)(dst + (size_t)off * 8) = s;
}

// ---------------------------------------------------------------------------
// Kernel 2: C = A(bf16,[M,K]) @ W(bf16,[N,K])^T + bias.  BM=128, BK=64.
// m97 staging into XOR-16B-chunk-SWIZZLED LDS tiles: gl2lds dest linear,
// global source chunk = (lane&7)^rsub; fragment read chunk = (kk*4+lg)^(lm&7)
// MODE 0 (BN=128): fused QKV, N=3072.  Q,K natural [bh][s][64]; V -> Vt
//                  [bh][64][s] via transposed LDS epilogue, 16B/lane stores.
//                  Q is PRE-SCALED by 0.125*log2(e) (attn exp2-domain fold).
// MODE 2 (BN=64):  fp32 out [M,1024] (final projection), 512 blocks (2/CU).
// XCD-aware flat-grid swizzle: xcd=bid&7 owns 4 m-rows.
// ---------------------------------------------------------------------------
template<int BN, int MODE>
__global__ __launch_bounds__(256) void gemm_kernel(
    const short* __restrict__ A, const short* __restrict__ W,
    const float* __restrict__ bq, const float* __restrict__ bk,
    const float* __restrict__ bv, void* __restrict__ out,
    int M, int N, int K)
{
    constexpr int SM = (MODE == 0) ? 18432 : (8192 + BN * 64);
    __shared__ __align__(16) short smem[SM];
    short* As = smem;                                  // [128][64] swizzled
    short* Bs = smem + 8192;                           // [BN][64]  swizzled

    const int t    = threadIdx.x;
    const int lane = t & 63;
    const int wave = t >> 6;

    const int bid = blockIdx.x;
    const int by  = ((bid & 7) << 2) + ((bid >> 3) & 3);
    const int bx  = bid >> 5;
    const int m0 = by * 128;
    const int n0 = bx * BN;

    const int wm = (wave >> 1) * 64;
    const int wn = (wave & 1) * (BN / 2);
    constexpr int NJ  = BN / 32;       // acc cols per wave (4 or 2)
    constexpr int BIT = BN / 32;       // B staging insts per wave

    v4f acc[4][NJ] = {};

    // staging: inst i2 covers 8 rows; lane l -> row +(l>>3),
    // SOURCE chunk ((l&7)^(l>>3))*8 shorts  (inverse of the read swizzle)
    const int rsub = lane >> 3;
    const int csw  = ((lane & 7) ^ rsub) * 8;
    const short* Ag = A + (size_t)(m0 + wave * 32 + rsub) * K + csw;
    const short* Wg = W + (size_t)(n0 + wave * (BN / 4) + rsub) * K + csw;
    short* Asw = As + (wave * 32) * 64;
    short* Bsw = Bs + (wave * (BN / 4)) * 64;

    const int lm = lane & 15;
    const int lg = lane >> 4;
    const int lm7 = lm & 7;

    for (int k0 = 0; k0 < K; k0 += 64) {
        #pragma unroll
        for (int i2 = 0; i2 < 4; ++i2)
            gl2lds16(Ag + (size_t)(i2 * 8) * K + k0, Asw + i2 * 512);
        #pragma unroll
        for (int i2 = 0; i2 < BIT; ++i2)
            gl2lds16(Wg + (size_t)(i2 * 8) * K + k0, Bsw + i2 * 512);
        __syncthreads();   // drains vmcnt(0): tiles visible

        #pragma unroll
        for (int kk = 0; kk < 2; ++kk) {
            const int ch = (kk * 4 + lg) ^ lm7;      // swizzled 16B chunk
            short8 af[4], bf[NJ];
            #pragma unroll
            for (int i = 0; i < 4; ++i)
                af[i] = *(const short8*)((const char*)As + (wm + i * 16 + lm) * 128 + ch * 16);
            #pragma unroll
            for (int j = 0; j < NJ; ++j)
                bf[j] = *(const short8*)((const char*)Bs + (wn + j * 16 + lm) * 128 + ch * 16);
            #pragma unroll
            for (int i = 0; i < 4; ++i)
                #pragma unroll
                for (int j = 0; j < NJ; ++j)
                    acc[i][j] = __builtin_amdgcn_mfma_f32_16x16x32_bf16(af[i], bf[j], acc[i][j], 0, 0, 0);
        }
        __syncthreads();   // all reads done before next overwrite
    }

    const int sel = n0 >> 10;          // 0=Q 1=K 2=V (block-uniform, MODE 0)
    const float* bias = (MODE == 2) ? bq : (sel == 0) ? bq : (sel == 1) ? bk : bv;

    if constexpr (MODE == 2) {
        const int colb = n0 + wn + lm;
        const int rowb = m0 + wm + lg * 4;
        #pragma unroll
        for (int j = 0; j < NJ; ++j) {
            int col = colb + j * 16;
            float bv_ = bias[col];
            #pragma unroll
            for (int i = 0; i < 4; ++i)
                #pragma unroll
                for (int r = 0; r < 4; ++r)
                    ((float*)out)[(size_t)(rowb + i * 16 + r) * 1024 + col] = acc[i][j][r] + bv_;
        }
    } else {
        // bf16 via wave-private LDS region (72-padded); 16B/lane wide stores.
        short* Es = smem + wave * (64 * 72);
        const int cb = (n0 + wn) & 1023;
        #pragma unroll
        for (int j = 0; j < 4; ++j) {
            float bv_ = bias[cb + j * 16 + lm];
            #pragma unroll
            for (int i = 0; i < 4; ++i)
                #pragma unroll
                for (int r = 0; r < 4; ++r) {
                    float vv = acc[i][j][r] + bv_;
                    if (sel == 0) vv *= 0.1803368867f;   // 0.125*log2(e): exp2-domain Q
                    if (sel < 2)    // Es[s_local][d]
                        Es[(i * 16 + lg * 4 + r) * 72 + j * 16 + lm] = f2bf(vv);
                    else            // V: Es[d][s_local]  (transposed)
                        Es[(j * 16 + lm) * 72 + i * 16 + lg * 4 + r] = f2bf(vv);
                }
        }
        __asm__ __volatile__("s_waitcnt lgkmcnt(0)" ::: "memory");
        short* outQKV = (short*)out;           // [Qh | Kb | Vt]
        const int rl = lane >> 3;
        const int c8 = (lane & 7) * 8;
        const int h  = cb >> 6;
        const int b  = (m0 + wm) >> 11;
        const int bh = (b << 4) + h;
        if (sel < 2) {
            #pragma unroll
            for (int it = 0; it < 8; ++it) {
                int row_l = it * 8 + rl;
                short8 vrow = *(const short8*)&Es[row_l * 72 + c8];
                int s = (m0 + wm + row_l) & 2047;
                *(short8*)(outQKV + (size_t)sel * 4194304 +
                           ((size_t)bh * S_ + s) * DH_ + c8) = vrow;
            }
        } else {
            const int s0 = (m0 + wm) & 2047;
            #pragma unroll
            for (int it = 0; it < 8; ++it) {
                int d_l = it * 8 + rl;
                short8 vrow = *(const short8*)&Es[d_l * 72 + c8];
                *(short8*)(outQKV + (size_t)2 * 4194304 +
                           ((size_t)bh << 17) + ((size_t)d_l << 11) + s0 + c8) = vrow;
            }
        }
    }
}

// ---------------------------------------------------------------------------
// Kernel 3: causal flash attention, 8 waves x 16 q-rows, pure-DMA staging,
// DOUBLE-BUFFERED, one barrier per pair.
// Block = (bh, q-tile j): 128 q-rows, 512 threads; kv pairs of 128,
// npairs = j+1 (diagonal pair masked).
// K tile [128 rows][64 shorts]: LDS chunk c of row r = global chunk c^(r&7).
// V^T tile [64 rows][128 shorts]: LDS chunk c of row d = global piece
// c^(d&7) (LINEAR pieces, swizzle only).  Both staged by global_load_lds
// with per-lane pre-swizzled source, linear dest (both-sides involution).
// PV A-frag = two ds_read_b64 (pieces p0, p0+2; offset (lg&1)*8) — uniform
// 4 dwords/bank per instruction = conflict-free optimal.
// LDS 2 x 32KB = 64KB; 2 blocks/CU -> 16 waves/CU = 4/SIMD.
// Grid 512: lo=bid&255 -> xcd=lo&7, j from idx; (j,15-j) co-resident per CU.
// ---------------------------------------------------------------------------
__global__ __launch_bounds__(512, 2) void attn_kernel(
    const short* __restrict__ Q, const short* __restrict__ Kh,
    const short* __restrict__ Vt, short* __restrict__ ctx)
{
    __shared__ __align__(16) short sm[32768];   // 64 KB: 2 x (Kt 8192 | Vp 8192)

    const int t    = threadIdx.x;
    const int lane = t & 63;
    const int w    = t >> 6;                     // 0..7
    const int bid  = blockIdx.x;                 // 512 blocks

    const int lo  = bid & 255;
    const int xcd = lo & 7;
    const int idx = lo >> 3;                     // 0..31
    const int bh  = (xcd << 2) + (idx & 3);
    const int jb  = idx >> 2;                    // 0..7
    const int j   = (bid < 256) ? jb : (15 - jb);
    const int q0  = j * 128;
    const int npairs = j + 1;
    const int qr0 = q0 + w * 16;                 // this wave's 16 q-rows

    const int lm = lane & 15;
    const int lg = lane >> 4;

    const short* Qb = Q  + (size_t)bh * S_ * DH_;
    const short* Kb = Kh + (size_t)bh * S_ * DH_;
    const short* Vb = Vt + ((size_t)bh << 17);

    // ---- pure-DMA staging helpers ----
    // K: instr i2 covers rows w*16+i2*8 .. +7; lane l -> row +(l>>3),
    //    source chunk (l&7)^(l>>3)  (row&7 == l>>3 since row base % 8 == 0)
    const int rsubK = lane >> 3;                         // 0..7
    const int cswK  = ((lane & 7) ^ rsubK) * 8;          // swizzled src (shorts)
    auto stageK = [&](int kv0, short* Kt) {
        #pragma unroll
        for (int i2 = 0; i2 < 2; ++i2) {
            const int rb = w * 16 + i2 * 8;
            gl2lds16(Kb + (size_t)(kv0 + rb + rsubK) * 64 + cswK, Kt + rb * 64);
        }
    };
    // V: instr i2 covers rows w*8+i2*4 .. +3; lane l -> row +(l>>4),
    //    chunk l&15, source piece (l&15)^(row&7), row&7 = (l>>4)+i2*4
    const int r4V = lane >> 4;                           // 0..3
    const int c16 = lane & 15;
    auto stageV = [&](int kv0, short* Vp) {
        #pragma unroll
        for (int i2 = 0; i2 < 2; ++i2) {
            const int d  = w * 8 + i2 * 4 + r4V;
            const int cs = c16 ^ (d & 7);
            gl2lds16(Vb + ((size_t)d << 11) + kv0 + cs * 8,
                     Vp + (w * 8 + i2 * 4) * 128);
        }
    };

    // Q as B-operand (pre-scaled by 0.125*log2e at the QKV GEMM):
    // B[n=q=qr0+lm][k=kk*32+lg*8+s]
    short8 qf[2];
    #pragma unroll
    for (int kk = 0; kk < 2; ++kk)
        qf[kk] = *(const short8*)(Qb + (size_t)(qr0 + lm) * DH_ + kk * 32 + lg * 8);

    float m_i = -1e30f, l_i = 0.f;
    v4f o[4] = {};   // O^T[d = i*16+lg*4+r][q = lm]

    // ---- prologue: stage pair 0 into buf0 ----
    stageK(0, sm);
    stageV(0, sm + 8192);
    __syncthreads();            // drains vmcnt: buf0 visible

    const int s3   = lm & 7;
    const int off8 = (lg & 1) * 8;
    const int pb   = lg >> 1;

    int cur = 0;
    for (int it = 0; it < npairs; ++it) {
        const int kv0 = it * 128;
        const bool dpair = (it == npairs - 1);   // diagonal pair (masked)
        short* Kt  = sm + cur * 16384;
        short* Vp  = Kt + 8192;

        // ---- prefetch next pair into the idle buffer (fire-and-forget) ----
        if (it + 1 < npairs) {
            short* Ktn = sm + (cur ^ 1) * 16384;
            stageK(kv0 + 128, Ktn);
            stageV(kv0 + 128, Ktn + 8192);
        }

        // ---- V^T A-frags: two swizzled 8B reads each ----
        short8 vf[2][2][4];
        #pragma unroll
        for (int u = 0; u < 2; ++u)
            #pragma unroll
            for (int kk = 0; kk < 2; ++kk) {
                const int p0 = u * 8 + kk * 4 + pb;
                #pragma unroll
                for (int i = 0; i < 4; ++i) {
                    const char* row = (const char*)Vp + (i * 16 + lm) * 256;
                    short4_t a = *(const short4_t*)(row + ((p0 ^ s3) << 4) + off8);
                    short4_t b = *(const short4_t*)(row + (((p0 + 2) ^ s3) << 4) + off8);
                    vf[u][kk][i] = __builtin_shufflevector(a, b, 0, 1, 2, 3, 4, 5, 6, 7);
                }
            }

        // ---- S^T = K Q^T, both subtiles (16 MFMAs); kf from swizzled Kt ----
        v4f sc[2][4] = {};   // [u][jj]
        #pragma unroll
        for (int u = 0; u < 2; ++u) {
            short8 kf[2][4];
            #pragma unroll
            for (int kk = 0; kk < 2; ++kk)
                #pragma unroll
                for (int jj = 0; jj < 4; ++jj) {
                    const int row = u * 64 + jj * 16 + lm;
                    const int ch  = (kk * 4 + lg) ^ s3;
                    kf[kk][jj] = *(const short8*)((const char*)Kt + row * 128 + ch * 16);
                }
            #pragma unroll
            for (int kk = 0; kk < 2; ++kk)
                #pragma unroll
                for (int jj = 0; jj < 4; ++jj)
                    sc[u][jj] = __builtin_amdgcn_mfma_f32_16x16x32_bf16(kf[kk][jj], qf[kk], sc[u][jj], 0, 0, 0);
        }

        // one online-softmax step over 128 kv (in-lane 32 + 2 shuffles)
        float alpha;
        short8 pf[2][2];     // [u][kk]
        {
            float x[2][4][4];
            const int q = qr0 + lm;
            #pragma unroll
            for (int u = 0; u < 2; ++u)
                #pragma unroll
                for (int jj = 0; jj < 4; ++jj)
                    #pragma unroll
                    for (int r = 0; r < 4; ++r) {
                        float v = sc[u][jj][r];
                        if (dpair && (kv0 + u * 64 + jj * 16 + lg * 4 + r > q)) v = -1e30f;
                        x[u][jj][r] = v;
                    }
            // tree max over 32 in-lane values
            float m8[8];
            #pragma unroll
            for (int z = 0; z < 8; ++z) {
                const float* xz = x[z >> 2][z & 3];
                m8[z] = fmaxf(fmaxf(xz[0], xz[1]), fmaxf(xz[2], xz[3]));
            }
            float rm = fmaxf(fmaxf(fmaxf(m8[0], m8[1]), fmaxf(m8[2], m8[3])),
                             fmaxf(fmaxf(m8[4], m8[5]), fmaxf(m8[6], m8[7])));
            rm = fmaxf(rm, __shfl_xor(rm, 16, 64));
            rm = fmaxf(rm, __shfl_xor(rm, 32, 64));

            const float mn = fmaxf(m_i, rm);
            alpha = EXP2(m_i - mn);
            m_i = mn;

            // exp2 + tree sum
            float s8[8];
            #pragma unroll
            for (int z = 0; z < 8; ++z) {
                float* xz = x[z >> 2][z & 3];
                xz[0] = EXP2(xz[0] - mn); xz[1] = EXP2(xz[1] - mn);
                xz[2] = EXP2(xz[2] - mn); xz[3] = EXP2(xz[3] - mn);
                s8[z] = (xz[0] + xz[1]) + (xz[2] + xz[3]);
            }
            float rs = ((s8[0] + s8[1]) + (s8[2] + s8[3])) + ((s8[4] + s8[5]) + (s8[6] + s8[7]));
            rs += __shfl_xor(rs, 16, 64);
            rs += __shfl_xor(rs, 32, 64);
            l_i = l_i * alpha + rs;

            // truncating pack: pf[u][kk][jj] = x[u][2kk][jj], [4+jj]=x[u][2kk+1][jj]
            #pragma unroll
            for (int u = 0; u < 2; ++u)
                #pragma unroll
                for (int kk = 0; kk < 2; ++kk) {
                    union { short8 s; uint4 d; } pk;
                    pk.d.x = pack2(x[u][2 * kk][0],     x[u][2 * kk][1]);
                    pk.d.y = pack2(x[u][2 * kk][2],     x[u][2 * kk][3]);
                    pk.d.z = pack2(x[u][2 * kk + 1][0], x[u][2 * kk + 1][1]);
                    pk.d.w = pack2(x[u][2 * kk + 1][2], x[u][2 * kk + 1][3]);
                    pf[u][kk] = pk.s;
                }
        }

        #pragma unroll
        for (int i = 0; i < 4; ++i)
            o[i] *= alpha;

        // O^T += V^T P^T  (16 MFMAs)
        #pragma unroll
        for (int u = 0; u < 2; ++u)
            #pragma unroll
            for (int kk = 0; kk < 2; ++kk)
                #pragma unroll
                for (int i = 0; i < 4; ++i)
                    o[i] = __builtin_amdgcn_mfma_f32_16x16x32_bf16(vf[u][kk][i], pf[u][kk], o[i], 0, 0, 0);

        __syncthreads();   // drains next-pair DMAs (vmcnt, issued ~2k cyc ago)
                           // + all waves' reads of buf[cur] complete
        cur ^= 1;
    }

    // epilogue: ctx[b*S + q][hd*64 + d] = O/l, 8B stores (all waves)
    const int b = bh >> 4, hd = bh & 15;
    {
        const float inv = 1.f / l_i;
        const size_t base = ((size_t)(b * S_ + qr0 + lm) << 10) + (hd << 6) + lg * 4;
        #pragma unroll
        for (int i = 0; i < 4; ++i) {
            short4_t s4;
            #pragma unroll
            for (int r = 0; r < 4; ++r) s4[r] = f2bf(o[i][r] * inv);
            *(short4_t*)(ctx + base + i * 16) = s4;
        }
    }
}

// ---------------------------------------------------------------------------
extern "C" void kernel_launch(void* const* d_in, const int* in_sizes, int n_in,
                              void* d_out, int out_size, void* d_ws, size_t ws_size,
                              hipStream_t stream) {
    const float* X  = (const float*)d_in[0];
    const float* Wq = (const float*)d_in[2];
    const float* bq = (const float*)d_in[3];
    const float* Wk = (const float*)d_in[4];
    const float* bk = (const float*)d_in[5];
    const float* Wv = (const float*)d_in[6];
    const float* bv = (const float*)d_in[7];
    const float* Wo = (const float*)d_in[8];
    const float* bo = (const float*)d_in[9];
    float* out = (float*)d_out;

    short* ws  = (short*)d_ws;
    short* Xb  = ws;                          // X bf16, 4,194,304
    short* Wb  = Xb + 4194304;                // [Wq|Wk|Wv|Wo] bf16
    short* Qh  = Wb + 4194304;                // [bh][s][64]  (pre-scaled)
    short* Kb  = Qh + 4194304;                // [bh][s][64]
    short* Vt  = Kb + 4194304;                // [bh][64][s] (written by gemm)
    short* Ctx = Vt + 4194304;                // [b*s][1024]

    cast_kernel<<<4096, 256, 0, stream>>>(X, Wq, Wk, Wv, Wo, Xb, Wb);

    // fused QKV projection: flat grid 24*32 = 768, swizzled in-kernel
    gemm_kernel<128, 0><<<768, 256, 0, stream>>>(
        Xb, Wb, bq, bk, bv, Qh, M_, 3 * D_, D_);

    // 8-wave pure-DMA double-buffered attention: 512 blocks x 512 threads
    attn_kernel<<<512, 512, 0, stream>>>(Qh, Kb, Vt, Ctx);

    // output projection: flat grid 16*32 = 512, swizzled in-kernel (2/CU)
    gemm_kernel<64, 2><<<512, 256, 0, stream>>>(
        Ctx, Wb + 3145728, bo, bo, bo, out, M_, D_, D_);
}

// Round 9
// 193.147 us; speedup vs baseline: 1.0207x; 1.0207x over previous
//
#include <hip/hip_runtime.h>

// ---------------------------------------------------------------------------
// MultiHeadAttention: B=2, S=2048, H=16, Dh=64, D=1024, causal mask, fp32 I/O.
// R19: attention = wave-group kv-split.  8 waves/block: group A (waves 0-3)
//      processes kv-pairs [0,ha), group B (waves 4-7) pairs [ha,nt), each at
//      the R14-verified 32-q-per-wave compute shape (2x fewer LDS bytes and
//      VALU chains per unit work than R16's 16-q shape).  Each group stages
//      its own K/V tile (R14 DMA-K + reg-staged permuted V — R18's b64-read
//      V layout doubled bank conflicts, reverted) into its own 32KB LDS half.
//      mx = nt-ha <= 8 steps (was 16): per step the block retires TWO pairs
//      at the per-step cost of one R16 pair.  Only B owns the diagonal.
//      End merge = R12's verified (m,l,o) LDS merge, reusing K/V LDS.
//      GEMMs unchanged (R14 conflict-free swizzled staging, verified).
// ---------------------------------------------------------------------------

#define B_   2
#define S_   2048
#define H_   16
#define DH_  64
#define D_   1024
#define M_   (B_ * S_)          // 4096 rows

typedef __attribute__((ext_vector_type(8))) short short8;
typedef __attribute__((ext_vector_type(4))) short short4_t;
typedef float v4f __attribute__((ext_vector_type(4)));

__device__ __forceinline__ short f2bf(float f) {
    union { float f; unsigned u; } v; v.f = f;
    unsigned r = v.u + 0x7fffu + ((v.u >> 16) & 1u);  // round-to-nearest-even
    return (short)(r >> 16);
}

#if __has_builtin(__builtin_amdgcn_exp2f)
#define EXP2(x) __builtin_amdgcn_exp2f(x)
#else
#define EXP2(x) exp2f(x)
#endif

// pack two f32 -> dword of two truncated bf16 (low short = a, high = b)
__device__ __forceinline__ unsigned pack2(float a, float b) {
    return (__float_as_uint(a) >> 16) | (__float_as_uint(b) & 0xFFFF0000u);
}

// async 16B/lane global -> LDS DMA (lane l deposits at lds + l*16)
__device__ __forceinline__ void gl2lds16(const short* g, short* l) {
    __builtin_amdgcn_global_load_lds(
        (const __attribute__((address_space(1))) unsigned int*)g,
        (__attribute__((address_space(3))) unsigned int*)l,
        16, 0, 0);
}

// ---------------------------------------------------------------------------
// Kernel 1: cast X and Wq,Wk,Wv,Wo fp32 -> bf16.  8 elems/thread, 16B stores.
// ---------------------------------------------------------------------------
__global__ __launch_bounds__(256) void cast_kernel(
    const float* __restrict__ X,
    const float* __restrict__ Wq, const float* __restrict__ Wk,
    const float* __restrict__ Wv, const float* __restrict__ Wo,
    short* __restrict__ Xb, short* __restrict__ Wb)
{
    const int NX8 = (M_ * D_) / 8;      // 524,288
    const int NW8 = (D_ * D_) / 8;      // 131,072
    int idx = blockIdx.x * 256 + threadIdx.x;   // 1,048,576 threads

    const float* src; short* dst; int off;
    if (idx < NX8) { src = X; dst = Xb; off = idx; }
    else {
        int r = idx - NX8;
        int sel = r >> 17;
        int o = r & (NW8 - 1);
        src = (sel == 0) ? Wq : (sel == 1) ? Wk : (sel == 2) ? Wv : Wo;
        dst = Wb + sel * (D_ * D_);
        off = o;
    }
    float4 f0 = ((const float4*)src)[off * 2];
    float4 f1 = ((const float4*)src)[off * 2 + 1];
    short8 s;
    s[0] = f2bf(f0.x); s[1] = f2bf(f0.y); s[2] = f2bf(f0.z); s[3] = f2bf(f0.w);
    s[4] = f2bf(f1.x); s[5] = f2bf(f1.y); s[6] = f2bf(f1.z); s[7] = f2bf(f1.w);
    *(short8*)(dst + (size_t)off * 8) = s;
}

// ---------------------------------------------------------------------------
// Kernel 2: C = A(bf16,[M,K]) @ W(bf16,[N,K])^T + bias.  BM=128, BK=64.
// m97 staging into XOR-16B-chunk-SWIZZLED LDS tiles: gl2lds dest linear,
// global source chunk = (lane&7)^rsub; fragment read chunk = (kk*4+lg)^(lm&7)
// MODE 0 (BN=128): fused QKV, N=3072.  Q,K natural [bh][s][64]; V -> Vt
//                  [bh][64][s] via transposed LDS epilogue, 16B/lane stores.
//                  Q is PRE-SCALED by 0.125*log2(e) (attn exp2-domain fold).
// MODE 2 (BN=64):  fp32 out [M,1024] (final projection), 512 blocks (2/CU).
// XCD-aware flat-grid swizzle: xcd=bid&7 owns 4 m-rows.
// ---------------------------------------------------------------------------
template<int BN, int MODE>
__global__ __launch_bounds__(256) void gemm_kernel(
    const short* __restrict__ A, const short* __restrict__ W,
    const float* __restrict__ bq, const float* __restrict__ bk,
    const float* __restrict__ bv, void* __restrict__ out,
    int M, int N, int K)
{
    constexpr int SM = (MODE == 0) ? 18432 : (8192 + BN * 64);
    __shared__ __align__(16) short smem[SM];
    short* As = smem;                                  // [128][64] swizzled
    short* Bs = smem + 8192;                           // [BN][64]  swizzled

    const int t    = threadIdx.x;
    const int lane = t & 63;
    const int wave = t >> 6;

    const int bid = blockIdx.x;
    const int by  = ((bid & 7) << 2) + ((bid >> 3) & 3);
    const int bx  = bid >> 5;
    const int m0 = by * 128;
    const int n0 = bx * BN;

    const int wm = (wave >> 1) * 64;
    const int wn = (wave & 1) * (BN / 2);
    constexpr int NJ  = BN / 32;       // acc cols per wave (4 or 2)
    constexpr int BIT = BN / 32;       // B staging insts per wave

    v4f acc[4][NJ] = {};

    // staging: inst i2 covers 8 rows; lane l -> row +(l>>3),
    // SOURCE chunk ((l&7)^(l>>3))*8 shorts  (inverse of the read swizzle)
    const int rsub = lane >> 3;
    const int csw  = ((lane & 7) ^ rsub) * 8;
    const short* Ag = A + (size_t)(m0 + wave * 32 + rsub) * K + csw;
    const short* Wg = W + (size_t)(n0 + wave * (BN / 4) + rsub) * K + csw;
    short* Asw = As + (wave * 32) * 64;
    short* Bsw = Bs + (wave * (BN / 4)) * 64;

    const int lm = lane & 15;
    const int lg = lane >> 4;
    const int lm7 = lm & 7;

    for (int k0 = 0; k0 < K; k0 += 64) {
        #pragma unroll
        for (int i2 = 0; i2 < 4; ++i2)
            gl2lds16(Ag + (size_t)(i2 * 8) * K + k0, Asw + i2 * 512);
        #pragma unroll
        for (int i2 = 0; i2 < BIT; ++i2)
            gl2lds16(Wg + (size_t)(i2 * 8) * K + k0, Bsw + i2 * 512);
        __syncthreads();   // drains vmcnt(0): tiles visible

        #pragma unroll
        for (int kk = 0; kk < 2; ++kk) {
            const int ch = (kk * 4 + lg) ^ lm7;      // swizzled 16B chunk
            short8 af[4], bf[NJ];
            #pragma unroll
            for (int i = 0; i < 4; ++i)
                af[i] = *(const short8*)((const char*)As + (wm + i * 16 + lm) * 128 + ch * 16);
            #pragma unroll
            for (int j = 0; j < NJ; ++j)
                bf[j] = *(const short8*)((const char*)Bs + (wn + j * 16 + lm) * 128 + ch * 16);
            #pragma unroll
            for (int i = 0; i < 4; ++i)
                #pragma unroll
                for (int j = 0; j < NJ; ++j)
                    acc[i][j] = __builtin_amdgcn_mfma_f32_16x16x32_bf16(af[i], bf[j], acc[i][j], 0, 0, 0);
        }
        __syncthreads();   // all reads done before next overwrite
    }

    const int sel = n0 >> 10;          // 0=Q 1=K 2=V (block-uniform, MODE 0)
    const float* bias = (MODE == 2) ? bq : (sel == 0) ? bq : (sel == 1) ? bk : bv;

    if constexpr (MODE == 2) {
        const int colb = n0 + wn + lm;
        const int rowb = m0 + wm + lg * 4;
        #pragma unroll
        for (int j = 0; j < NJ; ++j) {
            int col = colb + j * 16;
            float bv_ = bias[col];
            #pragma unroll
            for (int i = 0; i < 4; ++i)
                #pragma unroll
                for (int r = 0; r < 4; ++r)
                    ((float*)out)[(size_t)(rowb + i * 16 + r) * 1024 + col] = acc[i][j][r] + bv_;
        }
    } else {
        // bf16 via wave-private LDS region (72-padded); 16B/lane wide stores.
        short* Es = smem + wave * (64 * 72);
        const int cb = (n0 + wn) & 1023;
        #pragma unroll
        for (int j = 0; j < 4; ++j) {
            float bv_ = bias[cb + j * 16 + lm];
            #pragma unroll
            for (int i = 0; i < 4; ++i)
                #pragma unroll
                for (int r = 0; r < 4; ++r) {
                    float vv = acc[i][j][r] + bv_;
                    if (sel == 0) vv *= 0.1803368867f;   // 0.125*log2(e): exp2-domain Q
                    if (sel < 2)    // Es[s_local][d]
                        Es[(i * 16 + lg * 4 + r) * 72 + j * 16 + lm] = f2bf(vv);
                    else            // V: Es[d][s_local]  (transposed)
                        Es[(j * 16 + lm) * 72 + i * 16 + lg * 4 + r] = f2bf(vv);
                }
        }
        __asm__ __volatile__("s_waitcnt lgkmcnt(0)" ::: "memory");
        short* outQKV = (short*)out;           // [Qh | Kb | Vt]
        const int rl = lane >> 3;
        const int c8 = (lane & 7) * 8;
        const int h  = cb >> 6;
        const int b  = (m0 + wm) >> 11;
        const int bh = (b << 4) + h;
        if (sel < 2) {
            #pragma unroll
            for (int it = 0; it < 8; ++it) {
                int row_l = it * 8 + rl;
                short8 vrow = *(const short8*)&Es[row_l * 72 + c8];
                int s = (m0 + wm + row_l) & 2047;
                *(short8*)(outQKV + (size_t)sel * 4194304 +
                           ((size_t)bh * S_ + s) * DH_ + c8) = vrow;
            }
        } else {
            const int s0 = (m0 + wm) & 2047;
            #pragma unroll
            for (int it = 0; it < 8; ++it) {
                int d_l = it * 8 + rl;
                short8 vrow = *(const short8*)&Es[d_l * 72 + c8];
                *(short8*)(outQKV + (size_t)2 * 4194304 +
                           ((size_t)bh << 17) + ((size_t)d_l << 11) + s0 + c8) = vrow;
            }
        }
    }
}

// ---------------------------------------------------------------------------
// Kernel 3: causal flash attention, wave-group kv-split.
// Block = (bh, q-tile j): 128 q-rows, 512 threads = 2 groups x 4 waves.
// Group A (waves 0-3): kv pairs [0, ha); group B (waves 4-7): [ha, nt);
// nt = j+1, ha = nt>>1 (B owns the diagonal pair; A is provably strictly
// below the diagonal).  Wave wg in each group owns q-rows qr0 = q0+wg*32
// (R14 32-q compute shape, byte-identical: qf[2][2], sc[2][2][4], o[2][4]).
// Each group stages its own tiles into its 32KB LDS half: K [128][64] via
// global_load_lds source-side XOR-16B-chunk swizzle; V^T [64][128] reg-
// staged into permuted+swizzled LDS (R14 layout; single b128 PV frag read).
// Loop mx = nt-ha <= 8 steps, 2 barriers/step; A idles (barriers only) when
// tI >= ha.  End: B -> LDS (m,l,o), A merges (R12 formula) + epilogue.
// LDS 64KB -> 2 blocks/CU = 16 waves/CU = 4/SIMD at ~104 VGPR.
// Grid 512: lo=bid&255 -> xcd=lo&7, j from idx; (j,15-j) co-resident per CU.
// ---------------------------------------------------------------------------
__global__ __launch_bounds__(512, 2) void attn_kernel(
    const short* __restrict__ Q, const short* __restrict__ Kh,
    const short* __restrict__ Vt, short* __restrict__ ctx)
{
    __shared__ __align__(16) short sm[32768];   // 64KB: group g at sm+g*16384

    const int t    = threadIdx.x;
    const int lane = t & 63;
    const int w    = t >> 6;                     // 0..7
    const int wg   = w & 3;                      // wave within group
    const int g    = w >> 2;                     // 0 = A, 1 = B
    const int bid  = blockIdx.x;                 // 512 blocks

    const int lo  = bid & 255;
    const int xcd = lo & 7;
    const int idx = lo >> 3;                     // 0..31
    const int bh  = (xcd << 2) + (idx & 3);
    const int jb  = idx >> 2;                    // 0..7
    const int j   = (bid < 256) ? jb : (15 - jb);
    const int q0  = j * 128;
    const int nt  = j + 1;                       // total kv pairs (of 128)
    const int ha  = nt >> 1;                     // A: [0,ha)  B: [ha,nt)
    const int mx  = nt - ha;                     // loop steps (>= ha)
    const int pb  = g ? ha : 0;                  // group's first pair index
    const int np  = g ? (nt - ha) : ha;          // group's pair count
    const int qr0 = q0 + wg * 32;                // this wave's 32 q-rows

    const int lm = lane & 15;
    const int lg = lane >> 4;

    short* Kt = sm + g * 16384;                  // [128][64] swizzled
    short* Vp = Kt + 8192;                       // [64][128] permuted+swizzled

    const short* Qb = Q  + (size_t)bh * S_ * DH_;
    const short* Kb = Kh + (size_t)bh * S_ * DH_;
    const short* Vb = Vt + ((size_t)bh << 17);

    // ---- staging helpers (R14 layouts, wg in place of w) ----
    const int rsubK = lane >> 3;                         // 0..7
    const int cswK  = ((lane & 7) ^ rsubK) * 8;          // swizzled src chunk
    const int dV    = wg * 16 + (lane >> 2);             // V^T row this thread owns
    const int s3V   = dV & 7;

    // Q as B-operand (pre-scaled by 0.125*log2e at the QKV GEMM):
    short8 qf[2][2];
    #pragma unroll
    for (int t2 = 0; t2 < 2; ++t2)
        #pragma unroll
        for (int kk = 0; kk < 2; ++kk)
            qf[t2][kk] = *(const short8*)(Qb + (size_t)(qr0 + t2 * 16 + lm) * DH_ + kk * 32 + lg * 8);

    float m_i[2] = {-1e30f, -1e30f}, l_i[2] = {0.f, 0.f};
    v4f o[2][4] = {};   // O^T[d = i*16+lg*4+r][q = t2*16+lm]

    for (int tI = 0; tI < mx; ++tI) {
        const bool act   = tI < np;              // group A idles past ha
        const int  kv0   = (pb + tI) * 128;
        const bool dpair = (g == 1) && (tI == mx - 1);   // diagonal (B only)

        if (act) {
            // ---- stage K rows [kv0,kv0+128) x 64d (wave wg: 32 rows) ----
            #pragma unroll
            for (int i2 = 0; i2 < 4; ++i2) {
                const int rb = wg * 32 + i2 * 8;
                gl2lds16(Kb + (size_t)(kv0 + rb + rsubK) * 64 + cswK, Kt + rb * 64);
            }
            // ---- stage V^T rows [wg*16, wg*16+16) x 128kv (perm+swz) ----
            short8 vld[4];
            #pragma unroll
            for (int m = 0; m < 4; ++m) {
                const int cm = (lane & 3) + 4 * m;           // 16B piece index
                vld[m] = *(const short8*)(Vb + (size_t)dV * 2048 + kv0 + cm * 8);
            }
            char* vrow = (char*)Vp + dV * 256;
            #pragma unroll
            for (int m = 0; m < 4; ++m) {
                const int cm = (lane & 3) + 4 * m;
                const int u  = cm >> 3, kk = (cm >> 2) & 1;
                const int q0off = ((cm & 1) << 4) + ((cm >> 1) & 1) * 4;  // shorts
                const int bA = (u * 64 + kk * 32 + q0off) * 2;            // bytes
                const int pA = ((((bA >> 4) ^ s3V) << 4) | (bA & 15));
                const int bB = bA + 16;
                const int pB = ((((bB >> 4) ^ s3V) << 4) | (bB & 15));
                *(short4_t*)(vrow + pA) = __builtin_shufflevector(vld[m], vld[m], 0, 1, 2, 3);
                *(short4_t*)(vrow + pB) = __builtin_shufflevector(vld[m], vld[m], 4, 5, 6, 7);
            }
        }
        __syncthreads();   // drains vmcnt+lgkm: both groups' tiles visible

        if (act) {
            // ---- V^T A-frags from Vp: one swizzled 16B read each ----
            short8 vf[2][2][4];
            #pragma unroll
            for (int u = 0; u < 2; ++u)
                #pragma unroll
                for (int kk = 0; kk < 2; ++kk)
                    #pragma unroll
                    for (int i = 0; i < 4; ++i) {
                        const int d = i * 16 + lm;
                        const int ch = (u * 8 + kk * 4 + lg) ^ (lm & 7);
                        vf[u][kk][i] = *(const short8*)((const char*)Vp + d * 256 + ch * 16);
                    }

            // ---- S^T = K Q^T, both subtiles (32 MFMAs) ----
            v4f sc[2][2][4] = {};   // [t2][u][jj]
            #pragma unroll
            for (int u = 0; u < 2; ++u) {
                short8 kf[2][4];
                #pragma unroll
                for (int kk = 0; kk < 2; ++kk)
                    #pragma unroll
                    for (int jj = 0; jj < 4; ++jj) {
                        const int row = u * 64 + jj * 16 + lm;
                        const int ch  = (kk * 4 + lg) ^ (lm & 7);
                        kf[kk][jj] = *(const short8*)((const char*)Kt + row * 128 + ch * 16);
                    }
                #pragma unroll
                for (int kk = 0; kk < 2; ++kk)
                    #pragma unroll
                    for (int t2 = 0; t2 < 2; ++t2)
                        #pragma unroll
                        for (int jj = 0; jj < 4; ++jj)
                            sc[t2][u][jj] = __builtin_amdgcn_mfma_f32_16x16x32_bf16(kf[kk][jj], qf[t2][kk], sc[t2][u][jj], 0, 0, 0);
            }

            // one online-softmax step per t2 over 128 kv
            float alpha[2];
            short8 pf[2][2][2];     // [t2][u][kk]
            #pragma unroll
            for (int t2 = 0; t2 < 2; ++t2) {
                float x[2][4][4];
                const int q = qr0 + t2 * 16 + lm;
                #pragma unroll
                for (int u = 0; u < 2; ++u)
                    #pragma unroll
                    for (int jj = 0; jj < 4; ++jj)
                        #pragma unroll
                        for (int r = 0; r < 4; ++r) {
                            float v = sc[t2][u][jj][r];
                            if (dpair && (kv0 + u * 64 + jj * 16 + lg * 4 + r > q)) v = -1e30f;
                            x[u][jj][r] = v;
                        }
                float m8[8];
                #pragma unroll
                for (int z = 0; z < 8; ++z) {
                    const float* xz = x[z >> 2][z & 3];
                    m8[z] = fmaxf(fmaxf(xz[0], xz[1]), fmaxf(xz[2], xz[3]));
                }
                float rm = fmaxf(fmaxf(fmaxf(m8[0], m8[1]), fmaxf(m8[2], m8[3])),
                                 fmaxf(fmaxf(m8[4], m8[5]), fmaxf(m8[6], m8[7])));
                rm = fmaxf(rm, __shfl_xor(rm, 16, 64));
                rm = fmaxf(rm, __shfl_xor(rm, 32, 64));

                const float mn = fmaxf(m_i[t2], rm);
                alpha[t2] = EXP2(m_i[t2] - mn);
                m_i[t2] = mn;

                float s8[8];
                #pragma unroll
                for (int z = 0; z < 8; ++z) {
                    float* xz = x[z >> 2][z & 3];
                    xz[0] = EXP2(xz[0] - mn); xz[1] = EXP2(xz[1] - mn);
                    xz[2] = EXP2(xz[2] - mn); xz[3] = EXP2(xz[3] - mn);
                    s8[z] = (xz[0] + xz[1]) + (xz[2] + xz[3]);
                }
                float rs = ((s8[0] + s8[1]) + (s8[2] + s8[3])) + ((s8[4] + s8[5]) + (s8[6] + s8[7]));
                rs += __shfl_xor(rs, 16, 64);
                rs += __shfl_xor(rs, 32, 64);
                l_i[t2] = l_i[t2] * alpha[t2] + rs;

                #pragma unroll
                for (int u = 0; u < 2; ++u)
                    #pragma unroll
                    for (int kk = 0; kk < 2; ++kk) {
                        union { short8 s; uint4 d; } pk;
                        pk.d.x = pack2(x[u][2 * kk][0],     x[u][2 * kk][1]);
                        pk.d.y = pack2(x[u][2 * kk][2],     x[u][2 * kk][3]);
                        pk.d.z = pack2(x[u][2 * kk + 1][0], x[u][2 * kk + 1][1]);
                        pk.d.w = pack2(x[u][2 * kk + 1][2], x[u][2 * kk + 1][3]);
                        pf[t2][u][kk] = pk.s;
                    }
            }

            #pragma unroll
            for (int t2 = 0; t2 < 2; ++t2)
                #pragma unroll
                for (int i = 0; i < 4; ++i)
                    o[t2][i] *= alpha[t2];

            // O^T += V^T P^T  (32 MFMAs)
            #pragma unroll
            for (int u = 0; u < 2; ++u)
                #pragma unroll
                for (int kk = 0; kk < 2; ++kk)
                    #pragma unroll
                    for (int t2 = 0; t2 < 2; ++t2)
                        #pragma unroll
                        for (int i = 0; i < 4; ++i)
                            o[t2][i] = __builtin_amdgcn_mfma_f32_16x16x32_bf16(vf[u][kk][i], pf[t2][u][kk], o[t2][i], 0, 0, 0);
        }
        __syncthreads();   // all LDS reads done before next step's staging
    }

    // ---- merge the two kv-halves: group B -> LDS, group A merges ----
    float* fb = (float*)sm;      // reuse K/V LDS: 4*64*36 floats = 36KB
    if (g == 1) {
        float* mp = &fb[(wg * 64 + lane) * 36];
        mp[0] = m_i[0]; mp[1] = l_i[0]; mp[2] = m_i[1]; mp[3] = l_i[1];
        #pragma unroll
        for (int t2 = 0; t2 < 2; ++t2)
            #pragma unroll
            for (int i = 0; i < 4; ++i)
                #pragma unroll
                for (int r = 0; r < 4; ++r)
                    mp[4 + t2 * 16 + i * 4 + r] = o[t2][i][r];
    }
    __syncthreads();
    if (g == 0) {
        const float* mp = &fb[(wg * 64 + lane) * 36];
        #pragma unroll
        for (int t2 = 0; t2 < 2; ++t2) {
            const float mo = mp[t2 * 2];
            const float lo = mp[t2 * 2 + 1];
            const float mn = fmaxf(m_i[t2], mo);
            const float sa = EXP2(m_i[t2] - mn);
            const float sb = EXP2(mo - mn);
            l_i[t2] = l_i[t2] * sa + lo * sb;
            #pragma unroll
            for (int i = 0; i < 4; ++i)
                #pragma unroll
                for (int r = 0; r < 4; ++r)
                    o[t2][i][r] = o[t2][i][r] * sa + mp[4 + t2 * 16 + i * 4 + r] * sb;
        }

        // epilogue: ctx[b*S + q][hd*64 + d] = O/l, 8B stores
        const int b = bh >> 4, hd = bh & 15;
        #pragma unroll
        for (int t2 = 0; t2 < 2; ++t2) {
            const float inv = 1.f / l_i[t2];
            const size_t base = ((size_t)(b * S_ + qr0 + t2 * 16 + lm) << 10) + (hd << 6) + lg * 4;
            #pragma unroll
            for (int i = 0; i < 4; ++i) {
                short4_t s4;
                #pragma unroll
                for (int r = 0; r < 4; ++r) s4[r] = f2bf(o[t2][i][r] * inv);
                *(short4_t*)(ctx + base + i * 16) = s4;
            }
        }
    }
}

// ---------------------------------------------------------------------------
extern "C" void kernel_launch(void* const* d_in, const int* in_sizes, int n_in,
                              void* d_out, int out_size, void* d_ws, size_t ws_size,
                              hipStream_t stream) {
    const float* X  = (const float*)d_in[0];
    const float* Wq = (const float*)d_in[2];
    const float* bq = (const float*)d_in[3];
    const float* Wk = (const float*)d_in[4];
    const float* bk = (const float*)d_in[5];
    const float* Wv = (const float*)d_in[6];
    const float* bv = (const float*)d_in[7];
    const float* Wo = (const float*)d_in[8];
    const float* bo = (const float*)d_in[9];
    float* out = (float*)d_out;

    short* ws  = (short*)d_ws;
    short* Xb  = ws;                          // X bf16, 4,194,304
    short* Wb  = Xb + 4194304;                // [Wq|Wk|Wv|Wo] bf16
    short* Qh  = Wb + 4194304;                // [bh][s][64]  (pre-scaled)
    short* Kb  = Qh + 4194304;                // [bh][s][64]
    short* Vt  = Kb + 4194304;                // [bh][64][s] (written by gemm)
    short* Ctx = Vt + 4194304;                // [b*s][1024]

    cast_kernel<<<4096, 256, 0, stream>>>(X, Wq, Wk, Wv, Wo, Xb, Wb);

    // fused QKV projection: flat grid 24*32 = 768, swizzled in-kernel
    gemm_kernel<128, 0><<<768, 256, 0, stream>>>(
        Xb, Wb, bq, bk, bv, Qh, M_, 3 * D_, D_);

    // wave-group kv-split attention: 512 blocks x 512 threads
    attn_kernel<<<512, 512, 0, stream>>>(Qh, Kb, Vt, Ctx);

    // output projection: flat grid 16*32 = 512, swizzled in-kernel (2/CU)
    gemm_kernel<64, 2><<<512, 256, 0, stream>>>(
        Ctx, Wb + 3145728, bo, bo, bo, out, M_, D_, D_);
}